// Round 1
// baseline (1541.836 us; speedup 1.0000x reference)
//
#include <hip/hip_runtime.h>

#define N 128
#define DIM 8192

// ---------------- Stage 1: ground metric matrix -----------------------------
// GM[i][j] = sim ? max(0, d2) : max(0, 200 - d2),  d2 = sum_k (A[i][k]-B[j][k])^2
__global__ __launch_bounds__(256) void gm_kernel(const float* __restrict__ A,
                                                 const float* __restrict__ B,
                                                 const int* __restrict__ t1,
                                                 const int* __restrict__ t2,
                                                 float* __restrict__ GM) {
    __shared__ float As[16][68];   // pad 68: float4-aligned, 2-way bank alias only (free)
    __shared__ float Bs[16][68];
    const int bi = blockIdx.y, bj = blockIdx.x;
    const int tid = threadIdx.x;
    const int tx = tid & 15;        // col within tile
    const int ty = tid >> 4;        // row within tile
    const int lr = tid >> 4;        // staging row
    const int lc = (tid & 15) * 4;  // staging col (float4)
    const float* arow = A + (bi * 16 + lr) * DIM;
    const float* brow = B + (bj * 16 + lr) * DIM;
    float acc = 0.f;
    for (int k0 = 0; k0 < DIM; k0 += 64) {
        float4 a4 = *(const float4*)(arow + k0 + lc);
        float4 b4 = *(const float4*)(brow + k0 + lc);
        __syncthreads();
        *(float4*)&As[lr][lc] = a4;
        *(float4*)&Bs[lr][lc] = b4;
        __syncthreads();
        #pragma unroll
        for (int kk = 0; kk < 64; ++kk) {
            float d = As[ty][kk] - Bs[tx][kk];
            acc = fmaf(d, d, acc);
        }
    }
    const int row = bi * 16 + ty;
    const int col = bj * 16 + tx;
    float gm = (t1[row] == t2[col]) ? fmaxf(0.f, acc) : fmaxf(0.f, 200.f - acc);
    GM[row * N + col] = gm;
}

// ---------------- Stage 2: Hungarian (max-weight perfect matching) ----------
// e-maxx O(n^3) min-cost formulation on a = -GM, float64, 1-indexed.
// One block, 128 threads: thread t owns column j = t+1.
__global__ __launch_bounds__(128) void km_kernel(const float* __restrict__ GM,
                                                 float* __restrict__ out) {
    __shared__ double u[N + 1], v[N + 1], minv[N + 1];
    __shared__ int p[N + 1], way[N + 1], used[N + 1];
    __shared__ int rowmatch[N + 1], argmax_s[N + 1];
    __shared__ double red_val[2];
    __shared__ int red_idx[2];

    const int t = threadIdx.x;   // 0..127
    const int j = t + 1;         // column 1..N

    // --- init: row reduction (u[i] = -max_j GM[i][j]) + per-row argmax ---
    {
        float best = -1.f; int bj_ = 0;
        const float* grow = GM + t * N;
        for (int jj = 0; jj < N; ++jj) {
            float g = grow[jj];
            if (g > best) { best = g; bj_ = jj; }
        }
        u[t + 1] = -(double)best;
        argmax_s[t + 1] = bj_ + 1;
        v[j] = 0.0;
        p[j] = 0;
        rowmatch[t + 1] = 0;
    }
    if (t == 0) { u[0] = 0.0; v[0] = 0.0; p[0] = 0; }
    __syncthreads();

    // --- greedy tight assignment (serial, cheap) ---
    if (t == 0) {
        for (int i = 1; i <= N; ++i) {
            int jb = argmax_s[i];
            if (p[jb] == 0) { p[jb] = i; rowmatch[i] = 1; }
        }
    }
    __syncthreads();

    // --- augment remaining rows ---
    for (int i = 1; i <= N; ++i) {
        if (rowmatch[i]) continue;          // uniform (shared read after barrier)
        minv[j] = 1e300;
        used[j] = 0;
        if (t == 0) { p[0] = i; used[0] = 0; }
        __syncthreads();
        int j0 = 0;
        while (true) {
            if (t == 0) used[j0] = 1;
            __syncthreads();
            const int i0 = p[j0];
            double dl = 1e300; int jl = 0;
            if (!used[j]) {
                double cur = -(double)GM[(i0 - 1) * N + (j - 1)] - u[i0] - v[j];
                if (cur < minv[j]) { minv[j] = cur; way[j] = j0; }
                dl = minv[j]; jl = j;
            }
            // min+argmin over 128 threads: wave shuffle then 2-wave combine
            double rv = dl; int ri = jl;
            #pragma unroll
            for (int off = 32; off > 0; off >>= 1) {
                double ov = __shfl_down(rv, off, 64);
                int oi = __shfl_down(ri, off, 64);
                if (ov < rv) { rv = ov; ri = oi; }
            }
            if ((t & 63) == 0) { red_val[t >> 6] = rv; red_idx[t >> 6] = ri; }
            __syncthreads();
            double delta; int j1;
            if (red_val[0] <= red_val[1]) { delta = red_val[0]; j1 = red_idx[0]; }
            else                          { delta = red_val[1]; j1 = red_idx[1]; }
            // potential update (p[j] distinct across used columns; j=0 via t0)
            if (used[j]) { u[p[j]] += delta; v[j] -= delta; }
            else         { minv[j] -= delta; }
            if (t == 0)  { u[p[0]] += delta; }
            __syncthreads();
            j0 = j1;
            if (p[j0] == 0) break;
        }
        if (t == 0) {                        // augment along way[] chain
            int jj = j0;
            while (jj) { int jp = way[jj]; p[jj] = p[jp]; jj = jp; }
        }
        __syncthreads();
    }

    // --- loss = sum_j GM[p[j]-1][j-1] / N ---
    double c = (double)GM[(p[j] - 1) * N + (j - 1)];
    #pragma unroll
    for (int off = 32; off > 0; off >>= 1) c += __shfl_down(c, off, 64);
    if ((t & 63) == 0) red_val[t >> 6] = c;
    __syncthreads();
    if (t == 0) out[0] = (float)((red_val[0] + red_val[1]) / (double)N);
}

extern "C" void kernel_launch(void* const* d_in, const int* in_sizes, int n_in,
                              void* d_out, int out_size, void* d_ws, size_t ws_size,
                              hipStream_t stream) {
    const float* A  = (const float*)d_in[0];   // (128, 8192) f32
    const float* B  = (const float*)d_in[1];   // (128, 8192) f32
    const int*   t1 = (const int*)d_in[2];     // (128,) i32
    const int*   t2 = (const int*)d_in[3];     // (128,) i32
    float* out = (float*)d_out;
    float* GM  = (float*)d_ws;                 // 128*128*4 = 64 KiB scratch

    dim3 grid(8, 8);
    gm_kernel<<<grid, 256, 0, stream>>>(A, B, t1, t2, GM);
    km_kernel<<<1, 128, 0, stream>>>(GM, out);
}

// Round 2
// 119.265 us; speedup vs baseline: 12.9279x; 12.9279x over previous
//
#include <hip/hip_runtime.h>

#define N 128
#define DIM 8192
#define NW 16           // waves in solve block
#define TCAP 512        // per-wave LDS cost-tile capacity (floats)

// ---------------- wave-sync helpers ----------------------------------------
__device__ __forceinline__ void wave_fence() {
    __threadfence_block();
    __builtin_amdgcn_wave_barrier();
}
__device__ __forceinline__ int selI(int a, int b, int idx) {      // idx uniform
    int t = (idx & 64) ? b : a;
    return __shfl(t, idx & 63, 64);
}
__device__ __forceinline__ double selD(double a, double b, int idx) {
    double t = (idx & 64) ? b : a;
    return __shfl(t, idx & 63, 64);
}
__device__ __forceinline__ double embed_key(double v, int j) {
    long long b = __double_as_longlong(v);
    return __longlong_as_double((b & ~127LL) | (long long)j);
}

// ---------------- Stage 1: d2 partials (split-K) ----------------------------
// grid (4,4,16): 32x32 output tile, K-chunk 512. 2x2 register tile per thread.
__global__ __launch_bounds__(256) void d2_partial(const float* __restrict__ A,
                                                  const float* __restrict__ B,
                                                  float* __restrict__ d2) {
    __shared__ float As[32][68];   // row stride 272 B (16B-aligned per row)
    __shared__ float Bs[32][68];
    const int tid = threadIdx.x;
    const int bi = blockIdx.y, bj = blockIdx.x, bk = blockIdx.z;
    const int tx = tid & 15, ty = tid >> 4;
    const int kbase = bk * 512;
    float a00 = 0.f, a01 = 0.f, a10 = 0.f, a11 = 0.f;
    for (int k0 = 0; k0 < 512; k0 += 64) {
        __syncthreads();
        #pragma unroll
        for (int s = 0; s < 2; ++s) {
            int idx = tid + s * 256;         // 0..511
            int r = idx >> 4;                // 0..31
            int c = (idx & 15) << 2;         // 0..60
            *(float4*)&As[r][c] = *(const float4*)&A[(bi * 32 + r) * DIM + kbase + k0 + c];
            *(float4*)&Bs[r][c] = *(const float4*)&B[(bj * 32 + r) * DIM + kbase + k0 + c];
        }
        __syncthreads();
        #pragma unroll
        for (int kk = 0; kk < 64; kk += 4) {
            float4 x0 = *(float4*)&As[2 * ty][kk];
            float4 x1 = *(float4*)&As[2 * ty + 1][kk];
            float4 y0 = *(float4*)&Bs[2 * tx][kk];
            float4 y1 = *(float4*)&Bs[2 * tx + 1][kk];
            float d;
            d = x0.x - y0.x; a00 = fmaf(d, d, a00);
            d = x0.y - y0.y; a00 = fmaf(d, d, a00);
            d = x0.z - y0.z; a00 = fmaf(d, d, a00);
            d = x0.w - y0.w; a00 = fmaf(d, d, a00);
            d = x0.x - y1.x; a01 = fmaf(d, d, a01);
            d = x0.y - y1.y; a01 = fmaf(d, d, a01);
            d = x0.z - y1.z; a01 = fmaf(d, d, a01);
            d = x0.w - y1.w; a01 = fmaf(d, d, a01);
            d = x1.x - y0.x; a10 = fmaf(d, d, a10);
            d = x1.y - y0.y; a10 = fmaf(d, d, a10);
            d = x1.z - y0.z; a10 = fmaf(d, d, a10);
            d = x1.w - y0.w; a10 = fmaf(d, d, a10);
            d = x1.x - y1.x; a11 = fmaf(d, d, a11);
            d = x1.y - y1.y; a11 = fmaf(d, d, a11);
            d = x1.z - y1.z; a11 = fmaf(d, d, a11);
            d = x1.w - y1.w; a11 = fmaf(d, d, a11);
        }
    }
    const int r0 = bi * 32 + 2 * ty, c0 = bj * 32 + 2 * tx;
    atomicAdd(&d2[r0 * N + c0],           a00);
    atomicAdd(&d2[r0 * N + c0 + 1],       a01);
    atomicAdd(&d2[(r0 + 1) * N + c0],     a10);
    atomicAdd(&d2[(r0 + 1) * N + c0 + 1], a11);
}

// ---------------- Stage 2: decompose + per-class Hungarian ------------------
// Single block, 16 waves. Each wave runs an exact wave-synchronous (no
// __syncthreads) rectangular Hungarian on one label-class. If any cross-label
// entry is positive (decomposition invalid) -> single task over all 128x128.
__global__ __launch_bounds__(1024) void solve_kernel(float* __restrict__ gmg,
                                                     const int* __restrict__ t1,
                                                     const int* __restrict__ t2,
                                                     float* __restrict__ out) {
    __shared__ int lbl1[N], lbl2[N];
    __shared__ int rowlist[N], collist[N];
    __shared__ int rcnt[64], ccnt[64], rstart[65], cstart[65], rcur[64], ccur[64];
    __shared__ int tasks[65];
    __shared__ int ntasks_s, flag_s;
    __shared__ double totals[NW];
    __shared__ float ctile[NW][TCAP];
    __shared__ int   claimw[NW][N];

    const int tid = threadIdx.x;
    if (tid < 64) { rcnt[tid] = 0; ccnt[tid] = 0; rcur[tid] = 0; ccur[tid] = 0; }
    if (tid == 0) { ntasks_s = 0; flag_s = 0; }
    if (tid < N)  { lbl1[tid] = t1[tid]; lbl2[tid] = t2[tid]; }
    __syncthreads();
    if (tid < N) {
        int l1 = lbl1[tid], l2 = lbl2[tid];
        if (l1 < 0 || l1 > 63 || l2 < 0 || l2 > 63) atomicOr(&flag_s, 1);
        atomicAdd(&rcnt[l1 & 63], 1);
        atomicAdd(&ccnt[l2 & 63], 1);
    }
    // transform d2 -> gm in place; detect positive cross-label entries
    for (int e = tid; e < N * N; e += 1024) {
        int i = e >> 7, j = e & 127;
        float v = gmg[e];
        bool same = (lbl1[i] == lbl2[j]);
        float g = same ? fmaxf(v, 0.f) : fmaxf(200.f - v, 0.f);
        if (!same && g > 0.f) atomicOr(&flag_s, 1);
        gmg[e] = g;
    }
    __threadfence();
    __syncthreads();
    if (tid == 0) {
        rstart[0] = 0; cstart[0] = 0;
        for (int c = 0; c < 64; ++c) {
            rstart[c + 1] = rstart[c] + rcnt[c];
            cstart[c + 1] = cstart[c] + ccnt[c];
        }
        int nt = 0;
        if (flag_s) tasks[nt++] = -1;   // fallback: one task = everything
        else for (int c = 0; c < 64; ++c)
            if (rcnt[c] > 0 && ccnt[c] > 0) tasks[nt++] = c;
        ntasks_s = nt;
    }
    __syncthreads();
    if (tid < N) {       // counting-sort scatter: rows/cols grouped by label
        int l1 = lbl1[tid] & 63;
        int p = atomicAdd(&rcur[l1], 1);
        rowlist[rstart[l1] + p] = tid;
        int l2 = lbl2[tid] & 63;
        int q = atomicAdd(&ccur[l2], 1);
        collist[cstart[l2] + q] = tid;
    }
    __syncthreads();

    const int w = tid >> 6, lane = tid & 63;
    const int ntasks = ntasks_s;
    double acc = 0.0;

    for (int tk = w; tk < ntasks; tk += NW) {
        const int c = tasks[tk];
        int rs, Rn, cs, Cn;
        if (c < 0) { rs = 0; Rn = N; cs = 0; Cn = N; }
        else { rs = rstart[c]; Rn = rcnt[c]; cs = cstart[c]; Cn = ccnt[c]; }
        const int* rl = rowlist + rs;
        const int* cl = collist + cs;
        const bool T  = (Rn > Cn);          // ensure n_ <= m_
        const int n_  = T ? Cn : Rn;
        const int m_  = T ? Rn : Cn;
        const bool tile = (n_ * m_ <= TCAP);
        float* Cw = ctile[w];
        int*  clm = claimw[w];

        auto offg = [&](int j) { return T ? rl[j] * N : cl[j]; };
        auto rbg  = [&](int i) { return T ? cl[i] : rl[i] * N; };

        if (tile) {
            for (int e = lane; e < n_ * m_; e += 64) {
                int i = e / m_, j = e - i * m_;
                Cw[e] = gmg[rbg(i) + offg(j)];
            }
        }
        wave_fence();

        const float* CM = tile ? Cw : gmg;
        const int je0 = lane, je1 = lane + 64;
        const bool cA = (je0 < m_), cB = (je1 < m_);
        const bool rA = (je0 < n_), rB = (je1 < n_);
        const int off0 = cA ? (tile ? je0 : offg(je0)) : 0;
        const int off1 = cB ? (tile ? je1 : offg(je1)) : 0;
        const int rb0  = rA ? (tile ? je0 * m_ : rbg(je0)) : 0;
        const int rb1  = rB ? (tile ? je1 * m_ : rbg(je1)) : 0;

        // ---- row reduction: u[i] = -max_j gm(i,j)  (gm >= 0) ----
        double u0 = 0.0, u1 = 0.0;
        if (rA) { float mx = 0.f; for (int j = 0; j < m_; ++j) mx = fmaxf(mx, CM[rb0 + (tile ? j : offg(j))]); u0 = -(double)mx; }
        if (rB) { float mx = 0.f; for (int j = 0; j < m_; ++j) mx = fmaxf(mx, CM[rb1 + (tile ? j : offg(j))]); u1 = -(double)mx; }

        // ---- col reduction: v[j] = min_i (cost(i,j) - u[i]) ----
        double v0 = 1e30, v1 = 1e30;
        for (int i = 0; i < n_; ++i) {
            int rbI = tile ? i * m_ : selI(rb0, rb1, i);
            double ui = selD(u0, u1, i);
            if (cA) v0 = fmin(v0, -(double)CM[rbI + off0] - ui);
            if (cB) v1 = fmin(v1, -(double)CM[rbI + off1] - ui);
        }

        // ---- greedy tight assignment (claim via LDS atomicMin) ----
        if (cA) clm[je0] = 0x7fffffff;
        if (cB) clm[je1] = 0x7fffffff;
        wave_fence();
        int jc0 = -1, jc1 = -1;
        for (int j = 0; j < m_; ++j) {
            double vj = selD(v0, v1, j);
            int ofj = tile ? j : selI(off0, off1, j);
            if (rA && jc0 < 0) { double s = -(double)CM[rb0 + ofj] - u0 - vj; if (s < 1e-7) jc0 = j; }
            if (rB && jc1 < 0) { double s = -(double)CM[rb1 + ofj] - u1 - vj; if (s < 1e-7) jc1 = j; }
        }
        if (rA && jc0 >= 0) atomicMin(&clm[jc0], je0);
        if (rB && jc1 >= 0) atomicMin(&clm[jc1], je1);
        wave_fence();
        int p0 = -1, p1 = -1;                 // matched row per owned col
        if (cA && clm[je0] != 0x7fffffff) p0 = clm[je0];
        if (cB && clm[je1] != 0x7fffffff) p1 = clm[je1];
        bool mr0 = (rA && jc0 >= 0 && clm[jc0] == je0);
        bool mr1 = (rB && jc1 >= 0 && clm[jc1] == je1);

        int mx2 = (n_ > m_) ? n_ : m_;
        int grp = 1; while (grp < mx2 && grp < 64) grp <<= 1;

        // ---- augmentation phases (phase-local delta reformulation) ----
        for (int ir = 0; ir < n_; ++ir) {
            if (selI(mr0 ? 1 : 0, mr1 ? 1 : 0, ir)) continue;
            double minv0 = 1e30, minv1 = 1e30;
            bool used0 = false, used1 = false;
            int way0 = -2, way1 = -2;
            double markD0 = -1.0, markD1 = -1.0, ent0 = -1.0, ent1 = -1.0;
            if (rA && je0 == ir) ent0 = 0.0;
            if (rB && je1 == ir) ent1 = 0.0;
            double D = 0.0;
            int i0 = ir, jprev = -1;
            int guard = 2 * m_ + 8;
            while (guard-- > 0) {
                int rbI = tile ? i0 * m_ : selI(rb0, rb1, i0);
                double ui = selD(u0, u1, i0);
                double base = D - ui;
                if (cA && !used0) { double cand = base - (double)CM[rbI + off0] - v0; if (cand < minv0) { minv0 = cand; way0 = jprev; } }
                if (cB && !used1) { double cand = base - (double)CM[rbI + off1] - v1; if (cand < minv1) { minv1 = cand; way1 = jprev; } }
                double k0d = (cA && !used0) ? embed_key(minv0, je0) : 1e30;
                double k1d = (cB && !used1) ? embed_key(minv1, je1) : 1e30;
                double kd = fmin(k0d, k1d);
                for (int o = 1; o < grp; o <<= 1) kd = fmin(kd, __shfl_xor(kd, o, 64));
                if (grp < 64) kd = __shfl(kd, 0, 64);      // uniformity
                long long kb = __double_as_longlong(kd);
                int j1 = (int)(kb & 127);
                double Dn = __longlong_as_double(kb & ~127LL);
                if (Dn > 1e29) break;                      // pathological guard
                D = Dn;
                int i1 = selI(p0, p1, j1);
                if (i1 < 0) {
                    // augment along way[] chain (endpoint col never marked)
                    int jj = j1;
                    while (true) {
                        int wp = selI(way0, way1, jj);
                        int pn = (wp < 0) ? ir : selI(p0, p1, wp);
                        if (cA && je0 == jj) p0 = pn;
                        if (cB && je1 == jj) p1 = pn;
                        if (wp < 0) break;
                        jj = wp;
                    }
                    if (rA && je0 == ir) mr0 = true;
                    if (rB && je1 == ir) mr1 = true;
                    break;
                }
                if (cA && je0 == j1) { used0 = true; markD0 = D; }
                if (cB && je1 == j1) { used1 = true; markD1 = D; }
                if (rA && je0 == i1) ent0 = D;
                if (rB && je1 == i1) ent1 = D;
                jprev = j1; i0 = i1;
            }
            // finalize potentials: tree rows / used cols
            if (rA && ent0   >= 0.0) u0 += D - ent0;
            if (rB && ent1   >= 0.0) u1 += D - ent1;
            if (cA && markD0 >= 0.0) v0 -= D - markD0;
            if (cB && markD1 >= 0.0) v1 -= D - markD1;
        }

        // ---- class value: sum gm(p[j], j) over matched cols ----
        int q0 = (p0 >= 0) ? p0 : 0;
        int ra1 = __shfl(rb0, q0 & 63, 64);
        int ra2 = __shfl(rb1, q0 & 63, 64);
        double val = 0.0;
        if (cA && p0 >= 0) { int rbP = tile ? p0 * m_ : ((q0 & 64) ? ra2 : ra1); val += (double)CM[rbP + off0]; }
        int q1 = (p1 >= 0) ? p1 : 0;
        int rb1s = __shfl(rb0, q1 & 63, 64);
        int rb2s = __shfl(rb1, q1 & 63, 64);
        if (cB && p1 >= 0) { int rbP = tile ? p1 * m_ : ((q1 & 64) ? rb2s : rb1s); val += (double)CM[rbP + off1]; }
        for (int o = 1; o < 64; o <<= 1) val += __shfl_xor(val, o, 64);
        acc += val;
    }

    if (lane == 0) totals[w] = acc;
    __syncthreads();
    if (tid == 0) {
        double s = 0.0;
        for (int i = 0; i < NW; ++i) s += totals[i];
        out[0] = (float)(s / (double)N);
    }
}

extern "C" void kernel_launch(void* const* d_in, const int* in_sizes, int n_in,
                              void* d_out, int out_size, void* d_ws, size_t ws_size,
                              hipStream_t stream) {
    const float* A  = (const float*)d_in[0];
    const float* B  = (const float*)d_in[1];
    const int*   t1 = (const int*)d_in[2];
    const int*   t2 = (const int*)d_in[3];
    float* out = (float*)d_out;
    float* ws  = (float*)d_ws;                 // d2 / gm scratch: 64 KiB

    hipMemsetAsync(ws, 0, N * N * sizeof(float), stream);
    d2_partial<<<dim3(4, 4, 16), 256, 0, stream>>>(A, B, ws);
    solve_kernel<<<1, 1024, 0, stream>>>(ws, t1, t2, out);
}